// Round 23
// baseline (140.462 us; speedup 1.0000x reference)
//
#include <hip/hip_runtime.h>
#include <hip/hip_fp16.h>

#define N_NODES   50000
#define N_EDGES   600000
#define N_GRAPHS  500
#define IN_DIM    64
#define D         128
#define N_CLASSES 10
#define N_PROTO   50
#define GRAPH_SZ  10
#define EPS_F     1e-4f
#define NC4       (N_NODES * IN_DIM / 4)              // 800000 float4s of x
#define GRP8      ((N_NODES + 7) / 8)                 // 6250
#define G16_TILES (N_NODES / 16)                      // 3125 (exact)
#define BKT       64                                  // slots per node bucket
#define NCB       196                                 // coarse buckets (nodes>>8)
#define CBCAP     4096                                // slots per coarse bucket
#define HBLK      392                                 // pass-1 hist blocks
#define EPB       ((N_EDGES + HBLK - 1) / HBLK)       // 1531 edges/block
#define KPT       ((EPB + 255) / 256)                 // 6 per thread
#define CONV_BLK  ((NC4 + 255) / 256)                 // 3125 conv blocks appended to hist

typedef _Float16 half4_t __attribute__((ext_vector_type(4)));
typedef _Float16 half8_t __attribute__((ext_vector_type(8)));
typedef float    f32x4   __attribute__((ext_vector_type(4)));

struct Params {
    const float* x; const int* esrc; const int* edst; const int* bat;
    const float* W0; const float* b0; const float* W1; const float* b1;
    const float* W2; const float* b2; const float* pe; const float* lw;
    float* out;
    _Float16 *bufA, *bufB, *xs, *Bp0, *Bp1, *Bp2;
    float *pg, *gsum;
    int *src_sorted, *indeg, *coarse, *cursor;
};

__device__ __forceinline__ float dis_of(const int* __restrict__ indeg, int n) {
    return rsqrtf(1.0f + (float)indeg[n]);
}

// ---------- pack W [K,128] fp32 -> MFMA B-fragment fp16 ----------
__device__ __forceinline__ void pack_one(const float* __restrict__ W,
                                         _Float16* __restrict__ Bp, int nks, int t) {
    int j = t & 7, l = (t >> 3) & 63;
    int rest = t >> 9;
    int s = rest % nks, c = rest / nks;
    int k = s * 32 + (l >> 4) * 8 + j;
    int col = c * 16 + (l & 15);
    Bp[t] = (_Float16)W[k * D + col];
}

// ---------- P0: zero cursors+gsum, pack weights, proto means ----------
__global__ void kw_p0(Params P) {
    int i = blockIdx.x * 256 + threadIdx.x;
    if (i < NCB) { P.cursor[i] = 0; return; }
    i -= NCB;
    if (i < N_GRAPHS * D) { P.gsum[i] = 0.f; return; }
    i -= N_GRAPHS * D;
    if (i < 8192)  { pack_one(P.W0, P.Bp0, IN_DIM / 32, i); return; }
    i -= 8192;
    if (i < 16384) { pack_one(P.W1, P.Bp1, D / 32, i); return; }
    i -= 16384;
    if (i < 16384) { pack_one(P.W2, P.Bp2, D / 32, i); return; }
    i -= 16384;
    if (i < N_PROTO * D) {
        int p = i >> 7, j = i & 127;
        float s = 0.f;
#pragma unroll
        for (int g = 0; g < GRAPH_SZ; ++g) s += P.pe[((size_t)p * GRAPH_SZ + g) * D + j];
        P.pg[i] = s * (1.0f / GRAPH_SZ);
    }
}

// ---------- P1: coarse histogram scatter; extra blocks do x->fp16 conv ----------
__global__ __launch_bounds__(256) void kw_hist(Params P) {
    if (blockIdx.x >= HBLK) {                 // conv-only blocks (no LDS path)
        int i = (blockIdx.x - HBLK) * 256 + threadIdx.x;
        if (i < NC4) {
            float4 v = ((const float4*)P.x)[i];
            half4_t h = { (_Float16)v.x, (_Float16)v.y, (_Float16)v.z, (_Float16)v.w };
            ((half4_t*)P.xs)[i] = h;
        }
        return;
    }
    __shared__ int hcnt[NCB];
    __shared__ int hbase[NCB];
    int tid = threadIdx.x;
    for (int i = tid; i < NCB; i += 256) hcnt[i] = 0;
    __syncthreads();
    int e0 = blockIdx.x * EPB;
    int e1 = e0 + EPB; if (e1 > N_EDGES) e1 = N_EDGES;
    int lr[KPT], pb[KPT], pl[KPT];
#pragma unroll
    for (int i = 0; i < KPT; ++i) {
        int e = e0 + i * 256 + tid;
        lr[i] = -1;
        if (e < e1) {
            int d = P.edst[e];
            int b = d >> 8;
            pb[i] = b;
            pl[i] = P.esrc[e] | ((d & 255) << 16);
            lr[i] = atomicAdd(&hcnt[b], 1);
        }
    }
    __syncthreads();
    for (int i = tid; i < NCB; i += 256)
        hbase[i] = hcnt[i] ? atomicAdd(&P.cursor[i], hcnt[i]) : 0;
    __syncthreads();
#pragma unroll
    for (int i = 0; i < KPT; ++i) {
        if (lr[i] >= 0) {
            int pos = hbase[pb[i]] + lr[i];
            if (pos < CBCAP) P.coarse[(pb[i] << 12) + pos] = pl[i];
        }
    }
}

// ---------- P2: per-coarse-bucket LDS sort -> node buckets + indeg ----------
__global__ __launch_bounds__(256) void kw_sort(Params P) {
    __shared__ int edges[CBCAP];
    __shared__ int nrank[256];
    int b = blockIdx.x, tid = threadIdx.x;
    int total = P.cursor[b]; if (total > CBCAP) total = CBCAP;
    for (int i = tid; i < total; i += 256) edges[i] = P.coarse[(b << 12) + i];
    nrank[tid] = 0;
    __syncthreads();
    for (int i = tid; i < total; i += 256) {
        int pl = edges[i];
        int dl = pl >> 16;
        int r = atomicAdd(&nrank[dl], 1);
        if (r < BKT) P.src_sorted[(((b << 8) | dl) << 6) + r] = pl & 0xFFFF;
    }
    __syncthreads();
    int node = (b << 8) + tid;
    if (node < N_NODES) P.indeg[node] = nrank[tid];
}

// ---------- P3: fused agg64 (wide) -> GEMM0(relu+b0) -> GEMM1(*dis) -> bufA ----------
__global__ __launch_bounds__(256, 8) void kw_a0g01(Params P) {
    __shared__ _Float16 xa_t[16][72];
    __shared__ _Float16 h1_t[16][136];
    int tid = threadIdx.x;
    int row0 = blockIdx.x * 16;
    int grp = tid >> 5, lane16 = tid & 15, hf = (tid >> 4) & 1;
    int j4 = lane16 * 4;

#pragma unroll
    for (int iter = 0; iter < 2; ++iter) {
        int nrel = iter * 8 + grp;
        int node = row0 + nrel;
        int cnt = P.indeg[node];
        int base = node << 6;
        float a0 = 0.f, a1 = 0.f, a2 = 0.f, a3 = 0.f;
        int k = hf;
        if (k < cnt) {
            int sc = P.src_sorted[base + k];
            float dc = dis_of(P.indeg, sc);
            half4_t vc = *(const half4_t*)&P.xs[(size_t)sc * IN_DIM + j4];
            for (k += 2; k < cnt; k += 2) {
                int sn = P.src_sorted[base + k];
                float dn = dis_of(P.indeg, sn);
                half4_t vn = *(const half4_t*)&P.xs[(size_t)sn * IN_DIM + j4];
                a0 = fmaf((float)vc[0], dc, a0);
                a1 = fmaf((float)vc[1], dc, a1);
                a2 = fmaf((float)vc[2], dc, a2);
                a3 = fmaf((float)vc[3], dc, a3);
                vc = vn; dc = dn;
            }
            a0 = fmaf((float)vc[0], dc, a0);
            a1 = fmaf((float)vc[1], dc, a1);
            a2 = fmaf((float)vc[2], dc, a2);
            a3 = fmaf((float)vc[3], dc, a3);
        }
        a0 += __shfl_xor(a0, 16);
        a1 += __shfl_xor(a1, 16);
        a2 += __shfl_xor(a2, 16);
        a3 += __shfl_xor(a3, 16);
        if (hf == 0) {
            half4_t hv = *(const half4_t*)&P.xs[(size_t)node * IN_DIM + j4];
            float dd = rsqrtf(1.0f + (float)cnt);
            half4_t r = { (_Float16)((fmaf((float)hv[0], dd, a0)) * dd),
                          (_Float16)((fmaf((float)hv[1], dd, a1)) * dd),
                          (_Float16)((fmaf((float)hv[2], dd, a2)) * dd),
                          (_Float16)((fmaf((float)hv[3], dd, a3)) * dd) };
            *(half4_t*)&xa_t[nrel][j4] = r;
        }
    }
    __syncthreads();

    int wave = tid >> 6, lane = tid & 63;
    int l15 = lane & 15;
    int kof = (lane >> 4) * 8;
    int rb  = (lane >> 4) * 4;
    {
        half8_t af0 = *(const half8_t*)&xa_t[l15][kof];
        half8_t af1 = *(const half8_t*)&xa_t[l15][32 + kof];
        f32x4 acc[2];
        acc[0] = (f32x4){0.f, 0.f, 0.f, 0.f};
        acc[1] = (f32x4){0.f, 0.f, 0.f, 0.f};
#pragma unroll
        for (int cc = 0; cc < 2; ++cc) {
            int c = wave * 2 + cc;
            half8_t b0f = *(const half8_t*)&P.Bp0[(size_t)((c * 2 + 0) * 64 + lane) * 8];
            half8_t b1f = *(const half8_t*)&P.Bp0[(size_t)((c * 2 + 1) * 64 + lane) * 8];
            acc[cc] = __builtin_amdgcn_mfma_f32_16x16x32_f16(af0, b0f, acc[cc], 0, 0, 0);
            acc[cc] = __builtin_amdgcn_mfma_f32_16x16x32_f16(af1, b1f, acc[cc], 0, 0, 0);
        }
#pragma unroll
        for (int cc = 0; cc < 2; ++cc) {
            int col = (wave * 2 + cc) * 16 + l15;
            float bv = P.b0[col];
#pragma unroll
            for (int r = 0; r < 4; ++r)
                h1_t[rb + r][col] = (_Float16)fmaxf(acc[cc][r] + bv, 0.f);
        }
    }
    __syncthreads();

    {
        half8_t af[4];
#pragma unroll
        for (int s = 0; s < 4; ++s)
            af[s] = *(const half8_t*)&h1_t[l15][s * 32 + kof];
        f32x4 acc[2];
        acc[0] = (f32x4){0.f, 0.f, 0.f, 0.f};
        acc[1] = (f32x4){0.f, 0.f, 0.f, 0.f};
#pragma unroll
        for (int cc = 0; cc < 2; ++cc) {
            int c = wave * 2 + cc;
#pragma unroll
            for (int s = 0; s < 4; ++s) {
                half8_t bf = *(const half8_t*)&P.Bp1[(size_t)((c * 4 + s) * 64 + lane) * 8];
                acc[cc] = __builtin_amdgcn_mfma_f32_16x16x32_f16(af[s], bf, acc[cc], 0, 0, 0);
            }
        }
        float dsc[4];
#pragma unroll
        for (int r = 0; r < 4; ++r) dsc[r] = dis_of(P.indeg, row0 + rb + r);
#pragma unroll
        for (int cc = 0; cc < 2; ++cc) {
            int col = (wave * 2 + cc) * 16 + l15;
#pragma unroll
            for (int r = 0; r < 4; ++r)
                P.bufA[(size_t)(row0 + rb + r) * D + col] = (_Float16)(acc[cc][r] * dsc[r]);
        }
    }
}

// ---------- P4: fused gather1 (wide) -> GEMM2(*dis) -> bufB ----------
__global__ __launch_bounds__(256, 8) void kw_g1g2(Params P) {
    __shared__ _Float16 h2_t[16][136];
    int tid = threadIdx.x;
    int row0 = blockIdx.x * 16;
    int grp = tid >> 5, lane16 = tid & 15, hf = (tid >> 4) & 1;
    int j8 = lane16 * 8;

#pragma unroll
    for (int iter = 0; iter < 2; ++iter) {
        int nrel = iter * 8 + grp;
        int node = row0 + nrel;
        int cnt = P.indeg[node];
        int base = node << 6;
        float a[8] = {0.f, 0.f, 0.f, 0.f, 0.f, 0.f, 0.f, 0.f};
        int k = hf;
        if (k < cnt) {
            int sc = P.src_sorted[base + k];
            half8_t vc = *(const half8_t*)&P.bufA[(size_t)sc * D + j8];
            for (k += 2; k < cnt; k += 2) {
                int sn = P.src_sorted[base + k];
                half8_t vn = *(const half8_t*)&P.bufA[(size_t)sn * D + j8];
#pragma unroll
                for (int j = 0; j < 8; ++j) a[j] += (float)vc[j];
                vc = vn;
            }
#pragma unroll
            for (int j = 0; j < 8; ++j) a[j] += (float)vc[j];
        }
#pragma unroll
        for (int j = 0; j < 8; ++j) a[j] += __shfl_xor(a[j], 16);
        if (hf == 0) {
            float dd = rsqrtf(1.0f + (float)cnt);
            half8_t hv = *(const half8_t*)&P.bufA[(size_t)node * D + j8];
            half8_t r;
#pragma unroll
            for (int j = 0; j < 8; ++j)
                r[j] = (_Float16)fmaxf((a[j] + (float)hv[j]) * dd + P.b1[j8 + j], 0.f);
            *(half8_t*)&h2_t[nrel][j8] = r;
        }
    }
    __syncthreads();

    int wave = tid >> 6, lane = tid & 63;
    int l15 = lane & 15;
    int kof = (lane >> 4) * 8;
    int rb  = (lane >> 4) * 4;
    half8_t af[4];
#pragma unroll
    for (int s = 0; s < 4; ++s)
        af[s] = *(const half8_t*)&h2_t[l15][s * 32 + kof];
    f32x4 acc[2];
    acc[0] = (f32x4){0.f, 0.f, 0.f, 0.f};
    acc[1] = (f32x4){0.f, 0.f, 0.f, 0.f};
#pragma unroll
    for (int cc = 0; cc < 2; ++cc) {
        int c = wave * 2 + cc;
#pragma unroll
        for (int s = 0; s < 4; ++s) {
            half8_t bf = *(const half8_t*)&P.Bp2[(size_t)((c * 4 + s) * 64 + lane) * 8];
            acc[cc] = __builtin_amdgcn_mfma_f32_16x16x32_f16(af[s], bf, acc[cc], 0, 0, 0);
        }
    }
    float dsc[4];
#pragma unroll
    for (int r = 0; r < 4; ++r) dsc[r] = dis_of(P.indeg, row0 + rb + r);
#pragma unroll
    for (int cc = 0; cc < 2; ++cc) {
        int col = (wave * 2 + cc) * 16 + l15;
#pragma unroll
        for (int r = 0; r < 4; ++r)
            P.bufB[(size_t)(row0 + rb + r) * D + col] = (_Float16)(acc[cc][r] * dsc[r]);
    }
}

// ---------- P5: fused gather2 + per-graph TREE-REDUCE accumulate -> gsum ----------
__global__ __launch_bounds__(256, 8) void kw_g2r(Params P) {
    __shared__ float part[8][D];          // one row per node-group; no LDS atomics
    int tid = threadIdx.x;
    int n0 = blockIdx.x * 8;
    int grp = tid >> 5;
    int node = n0 + grp;                  // 6250*8 = 50000 exact
    int lane16 = tid & 15;
    int hf = (tid >> 4) & 1;
    int j8 = lane16 * 8;
    bool same = (P.bat[n0] == P.bat[n0 + 7]);   // block-uniform

    int cnt = P.indeg[node];
    int base = node << 6;
    float a[8] = {0.f, 0.f, 0.f, 0.f, 0.f, 0.f, 0.f, 0.f};
    int k = hf;
    if (k < cnt) {
        int sc = P.src_sorted[base + k];
        half8_t vc = *(const half8_t*)&P.bufB[(size_t)sc * D + j8];
        for (k += 2; k < cnt; k += 2) {
            int sn = P.src_sorted[base + k];
            half8_t vn = *(const half8_t*)&P.bufB[(size_t)sn * D + j8];
#pragma unroll
            for (int j = 0; j < 8; ++j) a[j] += (float)vc[j];
            vc = vn;
        }
#pragma unroll
        for (int j = 0; j < 8; ++j) a[j] += (float)vc[j];
    }
#pragma unroll
    for (int j = 0; j < 8; ++j) a[j] += __shfl_xor(a[j], 16);
    if (hf == 0) {
        float dd = rsqrtf(1.0f + (float)cnt);
        half8_t hv = *(const half8_t*)&P.bufB[(size_t)node * D + j8];
        float v[8];
#pragma unroll
        for (int j = 0; j < 8; ++j)
            v[j] = fmaxf((a[j] + (float)hv[j]) * dd + P.b2[j8 + j], 0.f);
        if (same) {
#pragma unroll
            for (int j = 0; j < 8; ++j) part[grp][j8 + j] = v[j];   // private row, no atomics
        } else {
            int g = P.bat[node];
#pragma unroll
            for (int j = 0; j < 8; ++j) atomicAdd(&P.gsum[(size_t)g * D + j8 + j], v[j]);
        }
    }
    if (same) {
        __syncthreads();
        // tree reduce rows 8 -> 1
#pragma unroll
        for (int step = 4; step >= 1; step >>= 1) {
            for (int i = tid; i < step * D; i += 256)
                part[i >> 7][i & 127] += part[(i >> 7) + step][i & 127];
            __syncthreads();
        }
        int g = P.bat[n0];
        for (int i = tid; i < D; i += 256)
            atomicAdd(&P.gsum[(size_t)g * D + i], part[0][i]);
    }
}

// ---------- P6: finish: mean + sim + logits ----------
__global__ void kw_finish(Params P) {
    __shared__ int sh[2];
    __shared__ float gs[D];
    __shared__ float sim[N_PROTO];
    int g = blockIdx.x;
    if (threadIdx.x == 0) {
        int lo = 0, hi = N_NODES;
        while (lo < hi) { int m = (lo + hi) >> 1; if (P.bat[m] < g) lo = m + 1; else hi = m; }
        sh[0] = lo;
        hi = N_NODES;
        while (lo < hi) { int m = (lo + hi) >> 1; if (P.bat[m] < g + 1) lo = m + 1; else hi = m; }
        sh[1] = lo;
    }
    __syncthreads();
    float cnt = fmaxf((float)(sh[1] - sh[0]), 1.0f);
    if (threadIdx.x < D) gs[threadIdx.x] = P.gsum[(size_t)g * D + threadIdx.x] / cnt;
    __syncthreads();
    int t = threadIdx.x;
    if (t < N_PROTO * 8) {                // 8 threads per proto
        int p = t >> 3, sub = t & 7;
        const float* q = P.pg + (size_t)p * D;
        float d2 = 0.f;
        int j0 = sub * 16;
#pragma unroll
        for (int j = 0; j < 16; ++j) {
            float df = gs[j0 + j] - q[j0 + j];
            d2 = fmaf(df, df, d2);
        }
        d2 += __shfl_xor(d2, 1);
        d2 += __shfl_xor(d2, 2);
        d2 += __shfl_xor(d2, 4);
        if (sub == 0) sim[p] = logf((d2 + 1.0f) / (d2 + EPS_F));
    }
    __syncthreads();
    if (t < N_CLASSES) {
        float s = 0.f;
#pragma unroll
        for (int p = 0; p < N_PROTO; ++p) s = fmaf(sim[p], P.lw[t * N_PROTO + p], s);
        P.out[(size_t)g * N_CLASSES + t] = s;
    }
}

extern "C" void kernel_launch(void* const* d_in, const int* in_sizes, int n_in,
                              void* d_out, int out_size, void* d_ws, size_t ws_size,
                              hipStream_t stream) {
    Params P;
    P.x    = (const float*)d_in[0];
    P.esrc = (const int*)d_in[1];
    P.edst = (const int*)d_in[1] + N_EDGES;
    P.bat  = (const int*)d_in[2];
    P.W0 = (const float*)d_in[3];  P.b0 = (const float*)d_in[4];
    P.W1 = (const float*)d_in[5];  P.b1 = (const float*)d_in[6];
    P.W2 = (const float*)d_in[7];  P.b2 = (const float*)d_in[8];
    P.pe = (const float*)d_in[9];  P.lw = (const float*)d_in[10];
    P.out = (float*)d_out;

    char* wsb = (char*)d_ws;
    P.bufA = (_Float16*)wsb;  wsb += (size_t)N_NODES * D * 2;
    P.bufB = (_Float16*)wsb;  wsb += (size_t)N_NODES * D * 2;
    P.xs   = (_Float16*)wsb;  wsb += (size_t)N_NODES * IN_DIM * 2;
    P.Bp0  = (_Float16*)wsb;  wsb += (size_t)IN_DIM * D * 2;
    P.Bp1  = (_Float16*)wsb;  wsb += (size_t)D * D * 2;
    P.Bp2  = (_Float16*)wsb;  wsb += (size_t)D * D * 2;
    P.pg   = (float*)wsb;     wsb += (size_t)N_PROTO * D * 4;
    P.gsum = (float*)wsb;     wsb += (size_t)N_GRAPHS * D * 4;
    P.src_sorted = (int*)wsb; wsb += (size_t)N_NODES * BKT * 4;   // 12.8 MB
    P.coarse     = (int*)wsb; wsb += (size_t)NCB * CBCAP * 4;     // 3.2 MB
    P.indeg      = (int*)wsb; wsb += (size_t)N_NODES * 4;
    P.cursor     = (int*)wsb; wsb += (size_t)NCB * 4;

    const int TB = 256;
    int p0_threads = NCB + N_GRAPHS * D + 8192 + 16384 + 16384 + N_PROTO * D;
    int p0_blocks  = (p0_threads + TB - 1) / TB;

    kw_p0<<<p0_blocks, TB, 0, stream>>>(P);
    kw_hist<<<HBLK + CONV_BLK, TB, 0, stream>>>(P);   // hist blocks + conv blocks
    kw_sort<<<NCB, TB, 0, stream>>>(P);
    kw_a0g01<<<G16_TILES, TB, 0, stream>>>(P);       // xs -> bufA (hs1)
    kw_g1g2<<<G16_TILES, TB, 0, stream>>>(P);        // bufA -> bufB (hs2)
    kw_g2r<<<GRP8, TB, 0, stream>>>(P);              // bufB -> gsum (tree-reduce)
    kw_finish<<<N_GRAPHS, 512, 0, stream>>>(P);      // gsum -> logits
}

// Round 27
// 130.808 us; speedup vs baseline: 1.0738x; 1.0738x over previous
//
#include <hip/hip_runtime.h>
#include <hip/hip_fp16.h>

#define N_NODES   50000
#define N_EDGES   600000
#define N_GRAPHS  500
#define IN_DIM    64
#define D         128
#define N_CLASSES 10
#define N_PROTO   50
#define GRAPH_SZ  10
#define EPS_F     1e-4f
#define NC4       (N_NODES * IN_DIM / 4)              // 800000 float4s of x
#define GRP8      ((N_NODES + 7) / 8)                 // 6250
#define G16_TILES (N_NODES / 16)                      // 3125 (exact)
#define BKT       64                                  // slots per node bucket
#define NCB       196                                 // coarse buckets (nodes>>8)
#define CBCAP     4096                                // slots per coarse bucket
#define HBLK      392                                 // pass-1 hist blocks
#define EPB       ((N_EDGES + HBLK - 1) / HBLK)       // 1531 edges/block
#define KPT       ((EPB + 255) / 256)                 // 6 per thread
#define CONV_BLK  ((NC4 + 255) / 256)                 // 3125 conv blocks appended to hist

typedef _Float16 half4_t __attribute__((ext_vector_type(4)));
typedef _Float16 half8_t __attribute__((ext_vector_type(8)));
typedef float    f32x4   __attribute__((ext_vector_type(4)));

struct Params {
    const float* x; const int* esrc; const int* edst; const int* bat;
    const float* W0; const float* b0; const float* W1; const float* b1;
    const float* W2; const float* b2; const float* pe; const float* lw;
    float* out;
    _Float16 *bufA, *bufB, *xs, *Bp0, *Bp1, *Bp2;
    float *pg;
    int *src_sorted, *indeg, *coarse, *cursor;
};

__device__ __forceinline__ float dis_of(const int* __restrict__ indeg, int n) {
    return rsqrtf(1.0f + (float)indeg[n]);
}

// ---------- pack W [K,128] fp32 -> MFMA B-fragment fp16 ----------
__device__ __forceinline__ void pack_one(const float* __restrict__ W,
                                         _Float16* __restrict__ Bp, int nks, int t) {
    int j = t & 7, l = (t >> 3) & 63;
    int rest = t >> 9;
    int s = rest % nks, c = rest / nks;
    int k = s * 32 + (l >> 4) * 8 + j;
    int col = c * 16 + (l & 15);
    Bp[t] = (_Float16)W[k * D + col];
}

// ---------- P0: zero cursors, pack weights, proto means ----------
__global__ void kw_p0(Params P) {
    int i = blockIdx.x * 256 + threadIdx.x;
    if (i < NCB) { P.cursor[i] = 0; return; }
    i -= NCB;
    if (i < 8192)  { pack_one(P.W0, P.Bp0, IN_DIM / 32, i); return; }
    i -= 8192;
    if (i < 16384) { pack_one(P.W1, P.Bp1, D / 32, i); return; }
    i -= 16384;
    if (i < 16384) { pack_one(P.W2, P.Bp2, D / 32, i); return; }
    i -= 16384;
    if (i < N_PROTO * D) {
        int p = i >> 7, j = i & 127;
        float s = 0.f;
#pragma unroll
        for (int g = 0; g < GRAPH_SZ; ++g) s += P.pe[((size_t)p * GRAPH_SZ + g) * D + j];
        P.pg[i] = s * (1.0f / GRAPH_SZ);
    }
}

// ---------- P1: coarse histogram scatter; extra blocks do x->fp16 conv ----------
__global__ __launch_bounds__(256) void kw_hist(Params P) {
    if (blockIdx.x >= HBLK) {                 // conv-only blocks (no LDS path)
        int i = (blockIdx.x - HBLK) * 256 + threadIdx.x;
        if (i < NC4) {
            float4 v = ((const float4*)P.x)[i];
            half4_t h = { (_Float16)v.x, (_Float16)v.y, (_Float16)v.z, (_Float16)v.w };
            ((half4_t*)P.xs)[i] = h;
        }
        return;
    }
    __shared__ int hcnt[NCB];
    __shared__ int hbase[NCB];
    int tid = threadIdx.x;
    for (int i = tid; i < NCB; i += 256) hcnt[i] = 0;
    __syncthreads();
    int e0 = blockIdx.x * EPB;
    int e1 = e0 + EPB; if (e1 > N_EDGES) e1 = N_EDGES;
    int lr[KPT], pb[KPT], pl[KPT];
#pragma unroll
    for (int i = 0; i < KPT; ++i) {
        int e = e0 + i * 256 + tid;
        lr[i] = -1;
        if (e < e1) {
            int d = P.edst[e];
            int b = d >> 8;
            pb[i] = b;
            pl[i] = P.esrc[e] | ((d & 255) << 16);
            lr[i] = atomicAdd(&hcnt[b], 1);
        }
    }
    __syncthreads();
    for (int i = tid; i < NCB; i += 256)
        hbase[i] = hcnt[i] ? atomicAdd(&P.cursor[i], hcnt[i]) : 0;
    __syncthreads();
#pragma unroll
    for (int i = 0; i < KPT; ++i) {
        if (lr[i] >= 0) {
            int pos = hbase[pb[i]] + lr[i];
            if (pos < CBCAP) P.coarse[(pb[i] << 12) + pos] = pl[i];
        }
    }
}

// ---------- P2: per-coarse-bucket LDS sort -> node buckets + indeg ----------
__global__ __launch_bounds__(256) void kw_sort(Params P) {
    __shared__ int edges[CBCAP];
    __shared__ int nrank[256];
    int b = blockIdx.x, tid = threadIdx.x;
    int total = P.cursor[b]; if (total > CBCAP) total = CBCAP;
    for (int i = tid; i < total; i += 256) edges[i] = P.coarse[(b << 12) + i];
    nrank[tid] = 0;
    __syncthreads();
    for (int i = tid; i < total; i += 256) {
        int pl = edges[i];
        int dl = pl >> 16;
        int r = atomicAdd(&nrank[dl], 1);
        if (r < BKT) P.src_sorted[(((b << 8) | dl) << 6) + r] = pl & 0xFFFF;
    }
    __syncthreads();
    int node = (b << 8) + tid;
    if (node < N_NODES) P.indeg[node] = nrank[tid];
}

// ---------- P3: fused agg64 (wide) -> GEMM0(relu+b0) -> GEMM1(*dis) -> bufA ----------
__global__ __launch_bounds__(256, 8) void kw_a0g01(Params P) {
    __shared__ _Float16 xa_t[16][72];
    __shared__ _Float16 h1_t[16][136];
    int tid = threadIdx.x;
    int row0 = blockIdx.x * 16;
    int grp = tid >> 5, lane16 = tid & 15, hf = (tid >> 4) & 1;
    int j4 = lane16 * 4;

#pragma unroll
    for (int iter = 0; iter < 2; ++iter) {
        int nrel = iter * 8 + grp;
        int node = row0 + nrel;
        int cnt = P.indeg[node];
        int base = node << 6;
        float a0 = 0.f, a1 = 0.f, a2 = 0.f, a3 = 0.f;
        int k = hf;
        if (k < cnt) {
            int sc = P.src_sorted[base + k];
            float dc = dis_of(P.indeg, sc);
            half4_t vc = *(const half4_t*)&P.xs[(size_t)sc * IN_DIM + j4];
            for (k += 2; k < cnt; k += 2) {
                int sn = P.src_sorted[base + k];
                float dn = dis_of(P.indeg, sn);
                half4_t vn = *(const half4_t*)&P.xs[(size_t)sn * IN_DIM + j4];
                a0 = fmaf((float)vc[0], dc, a0);
                a1 = fmaf((float)vc[1], dc, a1);
                a2 = fmaf((float)vc[2], dc, a2);
                a3 = fmaf((float)vc[3], dc, a3);
                vc = vn; dc = dn;
            }
            a0 = fmaf((float)vc[0], dc, a0);
            a1 = fmaf((float)vc[1], dc, a1);
            a2 = fmaf((float)vc[2], dc, a2);
            a3 = fmaf((float)vc[3], dc, a3);
        }
        a0 += __shfl_xor(a0, 16);
        a1 += __shfl_xor(a1, 16);
        a2 += __shfl_xor(a2, 16);
        a3 += __shfl_xor(a3, 16);
        if (hf == 0) {
            half4_t hv = *(const half4_t*)&P.xs[(size_t)node * IN_DIM + j4];
            float dd = rsqrtf(1.0f + (float)cnt);
            half4_t r = { (_Float16)((fmaf((float)hv[0], dd, a0)) * dd),
                          (_Float16)((fmaf((float)hv[1], dd, a1)) * dd),
                          (_Float16)((fmaf((float)hv[2], dd, a2)) * dd),
                          (_Float16)((fmaf((float)hv[3], dd, a3)) * dd) };
            *(half4_t*)&xa_t[nrel][j4] = r;
        }
    }
    __syncthreads();

    int wave = tid >> 6, lane = tid & 63;
    int l15 = lane & 15;
    int kof = (lane >> 4) * 8;
    int rb  = (lane >> 4) * 4;
    {
        half8_t af0 = *(const half8_t*)&xa_t[l15][kof];
        half8_t af1 = *(const half8_t*)&xa_t[l15][32 + kof];
        f32x4 acc[2];
        acc[0] = (f32x4){0.f, 0.f, 0.f, 0.f};
        acc[1] = (f32x4){0.f, 0.f, 0.f, 0.f};
#pragma unroll
        for (int cc = 0; cc < 2; ++cc) {
            int c = wave * 2 + cc;
            half8_t b0f = *(const half8_t*)&P.Bp0[(size_t)((c * 2 + 0) * 64 + lane) * 8];
            half8_t b1f = *(const half8_t*)&P.Bp0[(size_t)((c * 2 + 1) * 64 + lane) * 8];
            acc[cc] = __builtin_amdgcn_mfma_f32_16x16x32_f16(af0, b0f, acc[cc], 0, 0, 0);
            acc[cc] = __builtin_amdgcn_mfma_f32_16x16x32_f16(af1, b1f, acc[cc], 0, 0, 0);
        }
#pragma unroll
        for (int cc = 0; cc < 2; ++cc) {
            int col = (wave * 2 + cc) * 16 + l15;
            float bv = P.b0[col];
#pragma unroll
            for (int r = 0; r < 4; ++r)
                h1_t[rb + r][col] = (_Float16)fmaxf(acc[cc][r] + bv, 0.f);
        }
    }
    __syncthreads();

    {
        half8_t af[4];
#pragma unroll
        for (int s = 0; s < 4; ++s)
            af[s] = *(const half8_t*)&h1_t[l15][s * 32 + kof];
        f32x4 acc[2];
        acc[0] = (f32x4){0.f, 0.f, 0.f, 0.f};
        acc[1] = (f32x4){0.f, 0.f, 0.f, 0.f};
#pragma unroll
        for (int cc = 0; cc < 2; ++cc) {
            int c = wave * 2 + cc;
#pragma unroll
            for (int s = 0; s < 4; ++s) {
                half8_t bf = *(const half8_t*)&P.Bp1[(size_t)((c * 4 + s) * 64 + lane) * 8];
                acc[cc] = __builtin_amdgcn_mfma_f32_16x16x32_f16(af[s], bf, acc[cc], 0, 0, 0);
            }
        }
        float dsc[4];
#pragma unroll
        for (int r = 0; r < 4; ++r) dsc[r] = dis_of(P.indeg, row0 + rb + r);
#pragma unroll
        for (int cc = 0; cc < 2; ++cc) {
            int col = (wave * 2 + cc) * 16 + l15;
#pragma unroll
            for (int r = 0; r < 4; ++r)
                P.bufA[(size_t)(row0 + rb + r) * D + col] = (_Float16)(acc[cc][r] * dsc[r]);
        }
    }
}

// ---------- P4: fused gather1 (wide) -> GEMM2(*dis) -> bufB ----------
__global__ __launch_bounds__(256, 8) void kw_g1g2(Params P) {
    __shared__ _Float16 h2_t[16][136];
    int tid = threadIdx.x;
    int row0 = blockIdx.x * 16;
    int grp = tid >> 5, lane16 = tid & 15, hf = (tid >> 4) & 1;
    int j8 = lane16 * 8;

#pragma unroll
    for (int iter = 0; iter < 2; ++iter) {
        int nrel = iter * 8 + grp;
        int node = row0 + nrel;
        int cnt = P.indeg[node];
        int base = node << 6;
        float a[8] = {0.f, 0.f, 0.f, 0.f, 0.f, 0.f, 0.f, 0.f};
        int k = hf;
        if (k < cnt) {
            int sc = P.src_sorted[base + k];
            half8_t vc = *(const half8_t*)&P.bufA[(size_t)sc * D + j8];
            for (k += 2; k < cnt; k += 2) {
                int sn = P.src_sorted[base + k];
                half8_t vn = *(const half8_t*)&P.bufA[(size_t)sn * D + j8];
#pragma unroll
                for (int j = 0; j < 8; ++j) a[j] += (float)vc[j];
                vc = vn;
            }
#pragma unroll
            for (int j = 0; j < 8; ++j) a[j] += (float)vc[j];
        }
#pragma unroll
        for (int j = 0; j < 8; ++j) a[j] += __shfl_xor(a[j], 16);
        if (hf == 0) {
            float dd = rsqrtf(1.0f + (float)cnt);
            half8_t hv = *(const half8_t*)&P.bufA[(size_t)node * D + j8];
            half8_t r;
#pragma unroll
            for (int j = 0; j < 8; ++j)
                r[j] = (_Float16)fmaxf((a[j] + (float)hv[j]) * dd + P.b1[j8 + j], 0.f);
            *(half8_t*)&h2_t[nrel][j8] = r;
        }
    }
    __syncthreads();

    int wave = tid >> 6, lane = tid & 63;
    int l15 = lane & 15;
    int kof = (lane >> 4) * 8;
    int rb  = (lane >> 4) * 4;
    half8_t af[4];
#pragma unroll
    for (int s = 0; s < 4; ++s)
        af[s] = *(const half8_t*)&h2_t[l15][s * 32 + kof];
    f32x4 acc[2];
    acc[0] = (f32x4){0.f, 0.f, 0.f, 0.f};
    acc[1] = (f32x4){0.f, 0.f, 0.f, 0.f};
#pragma unroll
    for (int cc = 0; cc < 2; ++cc) {
        int c = wave * 2 + cc;
#pragma unroll
        for (int s = 0; s < 4; ++s) {
            half8_t bf = *(const half8_t*)&P.Bp2[(size_t)((c * 4 + s) * 64 + lane) * 8];
            acc[cc] = __builtin_amdgcn_mfma_f32_16x16x32_f16(af[s], bf, acc[cc], 0, 0, 0);
        }
    }
    float dsc[4];
#pragma unroll
    for (int r = 0; r < 4; ++r) dsc[r] = dis_of(P.indeg, row0 + rb + r);
#pragma unroll
    for (int cc = 0; cc < 2; ++cc) {
        int col = (wave * 2 + cc) * 16 + l15;
#pragma unroll
        for (int r = 0; r < 4; ++r)
            P.bufB[(size_t)(row0 + rb + r) * D + col] = (_Float16)(acc[cc][r] * dsc[r]);
    }
}

// ---------- P5: gather2: bufA = relu(dis*(sum bufB[src]+bufB[self])+b2) ----------
__global__ __launch_bounds__(256, 8) void kw_gather2(Params P) {
    int node = blockIdx.x * 8 + (threadIdx.x >> 5);
    if (node >= N_NODES) return;
    int lane16 = threadIdx.x & 15;
    int hf = (threadIdx.x >> 4) & 1;
    int j8 = lane16 * 8;
    int cnt = P.indeg[node];
    int base = node << 6;
    float a[8] = {0.f, 0.f, 0.f, 0.f, 0.f, 0.f, 0.f, 0.f};
    int k = hf;
    if (k < cnt) {
        int sc = P.src_sorted[base + k];
        half8_t vc = *(const half8_t*)&P.bufB[(size_t)sc * D + j8];
        for (k += 2; k < cnt; k += 2) {
            int sn = P.src_sorted[base + k];
            half8_t vn = *(const half8_t*)&P.bufB[(size_t)sn * D + j8];
#pragma unroll
            for (int j = 0; j < 8; ++j) a[j] += (float)vc[j];
            vc = vn;
        }
#pragma unroll
        for (int j = 0; j < 8; ++j) a[j] += (float)vc[j];
    }
#pragma unroll
    for (int j = 0; j < 8; ++j) a[j] += __shfl_xor(a[j], 16);
    if (hf == 0) {
        float dd = rsqrtf(1.0f + (float)cnt);
        half8_t hv = *(const half8_t*)&P.bufB[(size_t)node * D + j8];
        half8_t r;
#pragma unroll
        for (int j = 0; j < 8; ++j)
            r[j] = (_Float16)fmaxf((a[j] + (float)hv[j]) * dd + P.b2[j8 + j], 0.f);
        *(half8_t*)&P.bufA[(size_t)node * D + j8] = r;
    }
}

// ---------- P6: readout + sim + logits (1024 threads / graph, 8 partitions) ----------
__global__ __launch_bounds__(1024) void kw_readout(Params P) {
    __shared__ int sh[2];
    __shared__ float red[8][D];
    __shared__ float gs[D];
    __shared__ float sim[N_PROTO];
    const _Float16* h = P.bufA;
    int g = blockIdx.x;
    if (threadIdx.x == 0) {
        int lo = 0, hi = N_NODES;
        while (lo < hi) { int m = (lo + hi) >> 1; if (P.bat[m] < g) lo = m + 1; else hi = m; }
        sh[0] = lo;
        hi = N_NODES;
        while (lo < hi) { int m = (lo + hi) >> 1; if (P.bat[m] < g + 1) lo = m + 1; else hi = m; }
        sh[1] = lo;
    }
    __syncthreads();
    int s0 = sh[0], s1 = sh[1];
    int col = threadIdx.x & 127;
    int part = threadIdx.x >> 7;          // 0..7
    float sum = 0.f;
    for (int n = s0 + part; n < s1; n += 8) sum += (float)h[(size_t)n * D + col];
    red[part][col] = sum;
    __syncthreads();
    if (part == 0) {
        float tot = sum;
#pragma unroll
        for (int p = 1; p < 8; ++p) tot += red[p][col];
        gs[col] = tot / fmaxf((float)(s1 - s0), 1.0f);
    }
    __syncthreads();
    int t = threadIdx.x;
    if (t < N_PROTO * 8) {                // 8 threads per proto
        int p = t >> 3, sub = t & 7;
        const float* q = P.pg + (size_t)p * D;
        float d2 = 0.f;
        int j0 = sub * 16;
#pragma unroll
        for (int j = 0; j < 16; ++j) {
            float df = gs[j0 + j] - q[j0 + j];
            d2 = fmaf(df, df, d2);
        }
        d2 += __shfl_xor(d2, 1);
        d2 += __shfl_xor(d2, 2);
        d2 += __shfl_xor(d2, 4);
        if (sub == 0) sim[p] = logf((d2 + 1.0f) / (d2 + EPS_F));
    }
    __syncthreads();
    if (t < N_CLASSES) {
        float s = 0.f;
#pragma unroll
        for (int p = 0; p < N_PROTO; ++p) s = fmaf(sim[p], P.lw[t * N_PROTO + p], s);
        P.out[(size_t)g * N_CLASSES + t] = s;
    }
}

extern "C" void kernel_launch(void* const* d_in, const int* in_sizes, int n_in,
                              void* d_out, int out_size, void* d_ws, size_t ws_size,
                              hipStream_t stream) {
    Params P;
    P.x    = (const float*)d_in[0];
    P.esrc = (const int*)d_in[1];
    P.edst = (const int*)d_in[1] + N_EDGES;
    P.bat  = (const int*)d_in[2];
    P.W0 = (const float*)d_in[3];  P.b0 = (const float*)d_in[4];
    P.W1 = (const float*)d_in[5];  P.b1 = (const float*)d_in[6];
    P.W2 = (const float*)d_in[7];  P.b2 = (const float*)d_in[8];
    P.pe = (const float*)d_in[9];  P.lw = (const float*)d_in[10];
    P.out = (float*)d_out;

    char* wsb = (char*)d_ws;
    P.bufA = (_Float16*)wsb;  wsb += (size_t)N_NODES * D * 2;
    P.bufB = (_Float16*)wsb;  wsb += (size_t)N_NODES * D * 2;
    P.xs   = (_Float16*)wsb;  wsb += (size_t)N_NODES * IN_DIM * 2;
    P.Bp0  = (_Float16*)wsb;  wsb += (size_t)IN_DIM * D * 2;
    P.Bp1  = (_Float16*)wsb;  wsb += (size_t)D * D * 2;
    P.Bp2  = (_Float16*)wsb;  wsb += (size_t)D * D * 2;
    P.pg   = (float*)wsb;     wsb += (size_t)N_PROTO * D * 4;
    P.src_sorted = (int*)wsb; wsb += (size_t)N_NODES * BKT * 4;   // 12.8 MB
    P.coarse     = (int*)wsb; wsb += (size_t)NCB * CBCAP * 4;     // 3.2 MB
    P.indeg      = (int*)wsb; wsb += (size_t)N_NODES * 4;
    P.cursor     = (int*)wsb; wsb += (size_t)NCB * 4;

    const int TB = 256;
    int p0_threads = NCB + 8192 + 16384 + 16384 + N_PROTO * D;
    int p0_blocks  = (p0_threads + TB - 1) / TB;

    kw_p0<<<p0_blocks, TB, 0, stream>>>(P);
    kw_hist<<<HBLK + CONV_BLK, TB, 0, stream>>>(P);   // hist blocks + conv blocks
    kw_sort<<<NCB, TB, 0, stream>>>(P);
    kw_a0g01<<<G16_TILES, TB, 0, stream>>>(P);       // xs -> bufA (hs1)
    kw_g1g2<<<G16_TILES, TB, 0, stream>>>(P);        // bufA -> bufB (hs2)
    kw_gather2<<<GRP8, TB, 0, stream>>>(P);          // bufB -> bufA (h3)
    kw_readout<<<N_GRAPHS, 1024, 0, stream>>>(P);
}